// Round 14
// baseline (2700.449 us; speedup 1.0000x reference)
//
#include <hip/hip_runtime.h>
#include <math.h>

// Problem constants
constexpr int Tn  = 2048;  // time
constexpr int FCn = 512;   // context feats (g)
constexpr int FXn = 512;   // encoding feats (x)
constexpr int SXW = 72;    // (fallback) LDS stride bf16 sX/sW
constexpr int SYC = 136;   // LDS stride bf16 sY
constexpr int SZS = 132;   // LDS stride fp32 sZ

typedef __attribute__((ext_vector_type(8))) short  bf16x8;
typedef __attribute__((ext_vector_type(4))) float  f32x4;

// truncating fp32->bf16 pack: one v_perm_b32 per 2 elems
__device__ __forceinline__ unsigned pk2(float a, float b) {
  return __builtin_amdgcn_perm(__float_as_uint(b), __float_as_uint(a), 0x07060302u);
}
__device__ __forceinline__ uint4 pack8(float4 a, float4 b) {
  uint4 rv;
  rv.x = pk2(a.x, a.y); rv.y = pk2(a.z, a.w);
  rv.z = pk2(b.x, b.y); rv.w = pk2(b.z, b.w);
  return rv;
}

// async global->LDS 16B copy (dest = wave-uniform base; HW adds lane*16)
__device__ __forceinline__ void gll16(const unsigned short* g, void* lds) {
  __builtin_amdgcn_global_load_lds(
      (const __attribute__((address_space(1))) unsigned int*)g,
      (__attribute__((address_space(3))) unsigned int*)lds, 16, 0, 0);
}

__global__ void zero4(float* out) {
  if (threadIdx.x < 4) out[threadIdx.x] = 0.0f;
}

__global__ void finalize4(float* out) {
  int k = threadIdx.x;
  if (k < 4) out[k] *= 1.0f / (128.0f * (float)(Tn - (1 << k)));
}

// fp32 -> bf16 (trunc) converter, 4 elems/thread
__global__ void tobf16(const float* __restrict__ s, unsigned short* __restrict__ d) {
  int i = blockIdx.x * 256 + threadIdx.x;
  float4 v = ((const float4*)s)[i];
  uint2 p; p.x = pk2(v.x, v.y); p.y = pk2(v.z, v.w);
  ((uint2*)d)[i] = p;
}

// ---------------- v13 main kernel ----------------------------------------------
// R6 geometry (512 thr, 8 waves; Y wave tile 32j x 64g over gc=4 chunks of 128g;
// Z 32i x 64j; C bf16 direct; all operands bf16 from ws) + m201-style counted
// vmcnt pipeline: per Y phase issue 8 W-frag global loads (L2-resident W direct
// as B-operand) + 2 global_load_lds for the NEXT X buf, then s_waitcnt
// vmcnt(10) (drains only the previous buf's 2 gll16 -- the oldest), raw
// s_barrier, MFMA, raw s_barrier. No vmcnt(0) drain inside the loop.
// LDS: X dbuf 2x16K @0; sY [128][136]sh @32768; sZ fp32 overlays @0; sRed @67584.
__global__ __launch_bounds__(512, 4)
void infonce_v13(const unsigned short* __restrict__ Cb,
                 const unsigned short* __restrict__ Xb,
                 const unsigned short* __restrict__ Wb,
                 float* __restrict__ out)
{
  __shared__ __align__(16) unsigned char smem[67648];
  char* sm = (char*)smem;
  unsigned short* sY = (unsigned short*)(sm + 32768);
  float* sZ   = (float*)sm;
  float* sRed = (float*)(sm + 67584);

  const int tid = threadIdx.x;
  const int l   = tid & 63;
  const int w   = tid >> 6;     // 0..7
  const int r   = l & 15;
  const int h   = l >> 4;       // 0..3
  const int wr  = w >> 1;       // 0..3 (32-row group)
  const int wc  = w & 1;        // 0..1 (64-col group)

  // bijective chunked XCD swizzle: nwg = 8188 = 8*1023 + 4
  const int orig = blockIdx.x;
  const int xcd  = orig & 7;
  const int loc  = orig >> 3;
  const int wg   = (xcd < 4) ? (xcd * 1024 + loc) : (4096 + (xcd - 4) * 1023 + loc);
  const int k    = wg & 3;
  const int t    = wg >> 2;
  const int tau  = 1 << k;      // TAU = {1,2,4,8}
  if (t >= Tn - tau) return;    // uniform early-exit, before any barrier
  const int s = t + tau;

  // X staging source (pre-swizzled granule, self-inverse)
  const int gsw = (l & 7) ^ ((l >> 3) & 7);
  const size_t xstr = (size_t)Tn * FXn;
  const unsigned short* xs0 = Xb + (size_t)(w * 16 + (l >> 3)) * xstr
                              + (size_t)s * FXn + gsw * 8;
  const unsigned short* xs1 = xs0 + (size_t)8 * xstr;
  char* xd0 = sm + w * 2048;    // + CUR*16384; HW adds lane*16
  char* xd1 = xd0 + 1024;

  // W direct-read base (B-operand rows, 16B frags; W = 2MB, L2-resident)
  const unsigned short* wrow = Wb + ((size_t)k * 512 + wc * 64 + r) * 512;

  // C bf16 direct rows for Z A-frags
  const size_t cstr = (size_t)Tn * FCn;
  const unsigned short* c0h = Cb + (size_t)(wr * 32 + r) * cstr + (size_t)t * FCn;
  const unsigned short* c1h = c0h + (size_t)16 * cstr;

  f32x4 zacc[2][4];
#pragma unroll
  for (int a = 0; a < 2; ++a)
#pragma unroll
    for (int b = 0; b < 4; ++b) zacc[a][b] = f32x4{0.f, 0.f, 0.f, 0.f};

#define STG13(CUR, XC) do { \
    gll16(xs0 + (XC) * 64, xd0 + (CUR) * 16384); \
    gll16(xs1 + (XC) * 64, xd1 + (CUR) * 16384); } while (0)

#pragma unroll 1
  for (int gc = 0; gc < 4; ++gc) {
    f32x4 yacc[2][4];
#pragma unroll
    for (int a = 0; a < 2; ++a)
#pragma unroll
      for (int b = 0; b < 4; ++b) yacc[a][b] = f32x4{0.f, 0.f, 0.f, 0.f};

    STG13(0, 0);         // prologue stage for buf0
    __syncthreads();     // full drain once per gc

#pragma unroll 1
    for (int xc = 0; xc < 8; ++xc) {
      const int cur = xc & 1;
      // explicit W-frag loads (consumed by this phase's MFMA)
      bf16x8 wv[8];
#pragma unroll
      for (int q = 0; q < 8; ++q) {
        const int ks = q >> 2, bg = q & 3;
        wv[q] = *(const bf16x8*)(wrow + (size_t)(gc * 128 + bg * 16) * 512
                                 + xc * 64 + ks * 32 + h * 8);
      }
      if (xc < 7) {
        STG13(cur ^ 1, xc + 1);                         // next-buf loads in flight
        asm volatile("s_waitcnt vmcnt(10)" ::: "memory"); // drain ONLY prev 2 gll16
      } else {
        asm volatile("s_waitcnt vmcnt(8)" ::: "memory");
      }
      __builtin_amdgcn_s_barrier();    // raw barrier: no vmcnt(0) drain
      __builtin_amdgcn_sched_barrier(0);
      // MFMA on buf[cur]: A-frags from swizzled LDS, B-frags from wv
      {
        const char* bx = sm + cur * 16384;
#pragma unroll
        for (int ks = 0; ks < 2; ++ks) {
          const int cb = ((((ks << 2) + h) ^ (r & 7)) << 4);
          bf16x8 a0 = *(const bf16x8*)(bx + (wr * 32 + 0  + r) * 128 + cb);
          bf16x8 a1 = *(const bf16x8*)(bx + (wr * 32 + 16 + r) * 128 + cb);
#pragma unroll
          for (int bg = 0; bg < 4; ++bg) {
            yacc[0][bg] = __builtin_amdgcn_mfma_f32_16x16x32_bf16(
                a0, wv[ks * 4 + bg], yacc[0][bg], 0, 0, 0);
            yacc[1][bg] = __builtin_amdgcn_mfma_f32_16x16x32_bf16(
                a1, wv[ks * 4 + bg], yacc[1][bg], 0, 0, 0);
          }
        }
      }
      __builtin_amdgcn_s_barrier();    // all reads of buf[cur] done before rewrite
    }

    // write Y chunk to sY (D layout: row=..h*4+reg, col=..r), stride 136
#pragma unroll
    for (int aj = 0; aj < 2; ++aj)
#pragma unroll
      for (int bg = 0; bg < 4; ++bg)
#pragma unroll
        for (int reg = 0; reg < 4; ++reg)
          sY[(wr * 32 + aj * 16 + h * 4 + reg) * SYC + (wc * 64 + bg * 16 + r)] =
              (unsigned short)(__float_as_uint(yacc[aj][bg][reg]) >> 16);
    __syncthreads();

    // Z-GEMM partial: zacc += C(bf16 direct) * Y(sY); K=128 per gc, fully unrolled
#pragma unroll
    for (int ks = 0; ks < 4; ++ks) {
      const int go = ks * 32 + h * 8;
      bf16x8 a0 = *(const bf16x8*)(c0h + gc * 128 + go);
      bf16x8 a1 = *(const bf16x8*)(c1h + gc * 128 + go);
#pragma unroll
      for (int bj = 0; bj < 4; ++bj) {
        bf16x8 bb = *(const bf16x8*)(sY + (wc * 64 + bj * 16 + r) * SYC + go);
        zacc[0][bj] = __builtin_amdgcn_mfma_f32_16x16x32_bf16(a0, bb, zacc[0][bj], 0, 0, 0);
        zacc[1][bj] = __builtin_amdgcn_mfma_f32_16x16x32_bf16(a1, bb, zacc[1][bj], 0, 0, 0);
      }
    }
    __syncthreads();   // sY reads done before next gc's restage/rewrite
  }

  // ---- epilogue: dump Z (128x128) to sZ fp32, then row-lse ----
#pragma unroll
  for (int ai = 0; ai < 2; ++ai)
#pragma unroll
    for (int bj = 0; bj < 4; ++bj)
#pragma unroll
      for (int reg = 0; reg < 4; ++reg)
        sZ[(wr * 32 + ai * 16 + h * 4 + reg) * SZS + (wc * 64 + bj * 16 + r)] =
            zacc[ai][bj][reg];
  __syncthreads();

  // per-row lse over j (128 cols); 8 waves x 16 rows, 4 lanes per row
  const int row = w * 16 + (l >> 2);
  const int c0l = l & 3;
  float mx = -3.4e38f;
#pragma unroll
  for (int m = 0; m < 32; ++m) mx = fmaxf(mx, sZ[row * SZS + c0l + m * 4]);
  mx = fmaxf(mx, __shfl_xor(mx, 1));
  mx = fmaxf(mx, __shfl_xor(mx, 2));
  float sum = 0.f;
#pragma unroll
  for (int m = 0; m < 32; ++m) sum += __expf(sZ[row * SZS + c0l + m * 4] - mx);
  sum += __shfl_xor(sum, 1);
  sum += __shfl_xor(sum, 2);
  float val = (c0l == 0) ? (sZ[row * SZS + row] - (__logf(sum) + mx)) : 0.f;
#pragma unroll
  for (int off = 1; off < 64; off <<= 1) val += __shfl_xor(val, off);
  if (l == 0) sRed[w] = val;
  __syncthreads();
  if (tid == 0) {
    float bs = 0.f;
#pragma unroll
    for (int w2 = 0; w2 < 8; ++w2) bs += sRed[w2];
    atomicAdd(out + k, bs);
  }
#undef STG13
}

// ---------------- R5 fallback kernel (proven 1483 us) --------------------------
template <bool WBF>
__global__ __launch_bounds__(512, 4)
void infonce_main(const float* __restrict__ Cp, const float* __restrict__ Xp,
                  const void* __restrict__ Wp, float* __restrict__ out)
{
  __shared__ __align__(16) unsigned char smem[71680];
  unsigned short* sX = (unsigned short*)(smem);
  unsigned short* sW = (unsigned short*)(smem + 18432);
  unsigned short* sY = (unsigned short*)(smem + 36864);
  unsigned short* sC = (unsigned short*)(smem);
  float* sZ   = (float*)(smem);
  float* sRed = (float*)(smem + 67584);

  const int tid  = threadIdx.x;
  const int lane = tid & 63;
  const int wave = tid >> 6;
  const int r    = lane & 15;
  const int h    = lane >> 4;
  const int wr   = wave >> 1;
  const int wc   = wave & 1;

  const int orig = blockIdx.x;
  const int xcd  = orig & 7;
  const int loc  = orig >> 3;
  const int wg   = (xcd < 4) ? (xcd * 1024 + loc) : (4096 + (xcd - 4) * 1023 + loc);
  const int k    = wg & 3;
  const int t    = wg >> 2;
  const int tau  = 1 << k;
  if (t >= Tn - tau) return;

  const float* Cb = Cp + (size_t)t * FCn;
  const float* Xb = Xp + (size_t)(t + tau) * FXn;

  const int srow = tid >> 2;
  const int scol = (tid & 3) * 16;
  const float* xs = Xb + (size_t)srow * (Tn * FXn) + scol;
  unsigned short* xd = sX + srow * SXW + scol;
  unsigned short* wd = sW + srow * SXW + scol;
  const unsigned short* wsh = (const unsigned short*)Wp + (size_t)k * (FCn * FXn)
                              + (size_t)srow * FXn + scol;
  const float* wsf = (const float*)Wp + (size_t)k * (FCn * FXn)
                     + (size_t)srow * FXn + scol;
  const int crow0 = tid >> 4;
  const int ccol  = (tid & 15) * 8;
  const float* cs = Cb + (size_t)crow0 * (Tn * FCn) + ccol;
  unsigned short* cd = sC + crow0 * SYC + ccol;
  const size_t cstep = (size_t)32 * Tn * FCn;

  float4 px0, px1, px2, px3;
  float4 pw0, pw1, pw2, pw3;
  uint4  pb0, pb1;
  float4 pc0, pc1, pc2, pc3, pc4, pc5, pc6, pc7;

#define LOAD_X(XC) do { \
    const float4* _p = (const float4*)(xs + (XC) * 64); \
    px0 = _p[0]; px1 = _p[1]; px2 = _p[2]; px3 = _p[3]; } while (0)
#define LOAD_W(GC, XC) do { \
    if constexpr (WBF) { \
      const uint4* _p = (const uint4*)(wsh + (size_t)((GC) * 128) * FXn + (XC) * 64); \
      pb0 = _p[0]; pb1 = _p[1]; \
    } else { \
      const float4* _p = (const float4*)(wsf + (size_t)((GC) * 128) * FXn + (XC) * 64); \
      pw0 = _p[0]; pw1 = _p[1]; pw2 = _p[2]; pw3 = _p[3]; } } while (0)
#define STORE_XW() do { \
    *(uint4*)(xd)     = pack8(px0, px1); \
    *(uint4*)(xd + 8) = pack8(px2, px3); \
    if constexpr (WBF) { *(uint4*)(wd) = pb0; *(uint4*)(wd + 8) = pb1; } \
    else { *(uint4*)(wd) = pack8(pw0, pw1); *(uint4*)(wd + 8) = pack8(pw2, pw3); } \
  } while (0)
#define MFMA_YF() do { \
    _Pragma("unroll") \
    for (int ks = 0; ks < 2; ++ks) { \
      const int xoo = ks * 32 + h * 8; \
      bf16x8 a0 = *(const bf16x8*)(sX + (wr * 32 + 0  + r) * SXW + xoo); \
      bf16x8 a1 = *(const bf16x8*)(sX + (wr * 32 + 16 + r) * SXW + xoo); \
      _Pragma("unroll") \
      for (int bg = 0; bg < 4; ++bg) { \
        bf16x8 bb = *(const bf16x8*)(sW + (wc * 64 + bg * 16 + r) * SXW + xoo); \
        yacc[0][bg] = __builtin_amdgcn_mfma_f32_16x16x32_bf16(a0, bb, yacc[0][bg], 0, 0, 0); \
        yacc[1][bg] = __builtin_amdgcn_mfma_f32_16x16x32_bf16(a1, bb, yacc[1][bg], 0, 0, 0); \
      } } } while (0)

  f32x4 zacc[2][4];
#pragma unroll
  for (int a = 0; a < 2; ++a)
#pragma unroll
    for (int b = 0; b < 4; ++b) zacc[a][b] = f32x4{0.f, 0.f, 0.f, 0.f};

  LOAD_X(0); LOAD_W(0, 0);

  for (int gc = 0; gc < 4; ++gc) {
    f32x4 yacc[2][4];
#pragma unroll
    for (int a = 0; a < 2; ++a)
#pragma unroll
      for (int b = 0; b < 4; ++b) yacc[a][b] = f32x4{0.f, 0.f, 0.f, 0.f};

    for (int xc = 0; xc < 7; ++xc) {
      __syncthreads();
      STORE_XW();
      __syncthreads();
      LOAD_X(xc + 1); LOAD_W(gc, xc + 1);
      MFMA_YF();
    }
    __syncthreads();
    STORE_XW();
    __syncthreads();
    {
      const float4* p0 = (const float4*)(cs + 0 * cstep + gc * 128);
      const float4* p1 = (const float4*)(cs + 1 * cstep + gc * 128);
      const float4* p2 = (const float4*)(cs + 2 * cstep + gc * 128);
      const float4* p3 = (const float4*)(cs + 3 * cstep + gc * 128);
      pc0 = p0[0]; pc1 = p0[1];
      pc2 = p1[0]; pc3 = p1[1];
      pc4 = p2[0]; pc5 = p2[1];
      pc6 = p3[0]; pc7 = p3[1];
    }
    MFMA_YF();

#pragma unroll
    for (int aj = 0; aj < 2; ++aj)
#pragma unroll
      for (int bg = 0; bg < 4; ++bg)
#pragma unroll
        for (int reg = 0; reg < 4; ++reg)
          sY[(wr * 32 + aj * 16 + h * 4 + reg) * SYC + (wc * 64 + bg * 16 + r)] =
              (unsigned short)(__float_as_uint(yacc[aj][bg][reg]) >> 16);
    __syncthreads();
    *(uint4*)(cd + 0 * 32 * SYC) = pack8(pc0, pc1);
    *(uint4*)(cd + 1 * 32 * SYC) = pack8(pc2, pc3);
    *(uint4*)(cd + 2 * 32 * SYC) = pack8(pc4, pc5);
    *(uint4*)(cd + 3 * 32 * SYC) = pack8(pc6, pc7);
    __syncthreads();
    if (gc < 3) { LOAD_X(0); LOAD_W(gc + 1, 0); }
#pragma unroll
    for (int ks = 0; ks < 4; ++ks) {
      const int go = ks * 32 + h * 8;
      bf16x8 a0 = *(const bf16x8*)(sC + (wr * 32 + 0  + r) * SYC + go);
      bf16x8 a1 = *(const bf16x8*)(sC + (wr * 32 + 16 + r) * SYC + go);
#pragma unroll
      for (int bj = 0; bj < 4; ++bj) {
        bf16x8 bb = *(const bf16x8*)(sY + (wc * 64 + bj * 16 + r) * SYC + go);
        zacc[0][bj] = __builtin_amdgcn_mfma_f32_16x16x32_bf16(a0, bb, zacc[0][bj], 0, 0, 0);
        zacc[1][bj] = __builtin_amdgcn_mfma_f32_16x16x32_bf16(a1, bb, zacc[1][bj], 0, 0, 0);
      }
    }
  }
  __syncthreads();
#pragma unroll
  for (int ai = 0; ai < 2; ++ai)
#pragma unroll
    for (int bj = 0; bj < 4; ++bj)
#pragma unroll
      for (int reg = 0; reg < 4; ++reg)
        sZ[(wr * 32 + ai * 16 + h * 4 + reg) * SZS + (wc * 64 + bj * 16 + r)] =
            zacc[ai][bj][reg];
  __syncthreads();

  const int row = wave * 16 + (lane >> 2);
  const int c0l = lane & 3;
  float mx = -3.4e38f;
#pragma unroll
  for (int m = 0; m < 32; ++m) mx = fmaxf(mx, sZ[row * SZS + c0l + m * 4]);
  mx = fmaxf(mx, __shfl_xor(mx, 1));
  mx = fmaxf(mx, __shfl_xor(mx, 2));
  float sum = 0.f;
#pragma unroll
  for (int m = 0; m < 32; ++m) sum += __expf(sZ[row * SZS + c0l + m * 4] - mx);
  sum += __shfl_xor(sum, 1);
  sum += __shfl_xor(sum, 2);
  float val = (c0l == 0) ? (sZ[row * SZS + row] - (__logf(sum) + mx)) : 0.f;
#pragma unroll
  for (int off = 1; off < 64; off <<= 1) val += __shfl_xor(val, off);
  if (lane == 0) sRed[wave] = val;
  __syncthreads();
  if (tid == 0) {
    float bs = 0.f;
#pragma unroll
    for (int w2 = 0; w2 < 8; ++w2) bs += sRed[w2];
    atomicAdd(out + k, bs);
  }
#undef LOAD_X
#undef LOAD_W
#undef STORE_XW
#undef MFMA_YF
}

extern "C" void kernel_launch(void* const* d_in, const int* in_sizes, int n_in,
                              void* d_out, int out_size, void* d_ws, size_t ws_size,
                              hipStream_t stream) {
  const float* C = (const float*)d_in[0];
  const float* X = (const float*)d_in[1];
  const float* W = (const float*)d_in[2];
  // d_in[3] (bias) intentionally unused: j-independent bias cancels in Zdiag - lse
  float* out = (float*)d_out;

  const size_t NE = (size_t)128 * Tn * FXn;        // 134,217,728 elems (X and C)
  const size_t NW = (size_t)4 * FCn * FXn;         // 1,048,576 elems
  const size_t WS_W    = NW * 2;                   // 2 MB
  const size_t WS_FULL = WS_W + 2 * NE * 2;        // + Xbf + Cbf = 538,968,064

  hipLaunchKernelGGL(zero4, dim3(1), dim3(64), 0, stream, out);

  if (ws_size >= WS_FULL) {
    unsigned short* Wbf = (unsigned short*)d_ws;
    unsigned short* Xbf = (unsigned short*)((char*)d_ws + WS_W);
    unsigned short* Cbf = (unsigned short*)((char*)d_ws + WS_W + NE * 2);
    hipLaunchKernelGGL(tobf16, dim3((unsigned)(NW / 1024)), dim3(256), 0, stream, W, Wbf);
    hipLaunchKernelGGL(tobf16, dim3((unsigned)(NE / 1024)), dim3(256), 0, stream, X, Xbf);
    hipLaunchKernelGGL(tobf16, dim3((unsigned)(NE / 1024)), dim3(256), 0, stream, C, Cbf);
    hipLaunchKernelGGL(infonce_v13, dim3(2047 * 4), dim3(512), 0, stream,
                       Cbf, Xbf, Wbf, out);
  } else if (ws_size >= WS_W) {
    hipLaunchKernelGGL(tobf16, dim3((unsigned)(NW / 1024)), dim3(256), 0, stream,
                       W, (unsigned short*)d_ws);
    hipLaunchKernelGGL(infonce_main<true>, dim3(2047 * 4), dim3(512), 0, stream,
                       C, X, (const void*)d_ws, out);
  } else {
    hipLaunchKernelGGL(infonce_main<false>, dim3(2047 * 4), dim3(512), 0, stream,
                       C, X, (const void*)W, out);
  }
  hipLaunchKernelGGL(finalize4, dim3(1), dim3(64), 0, stream, out);
}

// Round 15
// 1392.324 us; speedup vs baseline: 1.9395x; 1.9395x over previous
//
#include <hip/hip_runtime.h>
#include <math.h>

// Problem constants
constexpr int Tn  = 2048;  // time
constexpr int FCn = 512;   // context feats (g)
constexpr int FXn = 512;   // encoding feats (x)
constexpr int SXW = 72;    // (fallback) LDS stride bf16 sX/sW
constexpr int SYC = 136;   // (fallback) LDS stride bf16 sY/sC
constexpr int SZS = 132;   // LDS stride (fp32) for sZ

typedef __attribute__((ext_vector_type(8))) short  bf16x8;
typedef __attribute__((ext_vector_type(4))) float  f32x4;

// truncating fp32->bf16 pack: one v_perm_b32 per 2 elems
__device__ __forceinline__ unsigned pk2(float a, float b) {
  return __builtin_amdgcn_perm(__float_as_uint(b), __float_as_uint(a), 0x07060302u);
}
__device__ __forceinline__ uint4 pack8(float4 a, float4 b) {
  uint4 rv;
  rv.x = pk2(a.x, a.y); rv.y = pk2(a.z, a.w);
  rv.z = pk2(b.x, b.y); rv.w = pk2(b.z, b.w);
  return rv;
}

// async global->LDS 16B copy (dest = wave-uniform base + lane*16)
__device__ __forceinline__ void gll16(const unsigned short* g, void* lds) {
  __builtin_amdgcn_global_load_lds(
      (const __attribute__((address_space(1))) unsigned int*)g,
      (__attribute__((address_space(3))) unsigned int*)lds, 16, 0, 0);
}

__global__ void zero4(float* out) {
  if (threadIdx.x < 4) out[threadIdx.x] = 0.0f;
}

__global__ void finalize4(float* out) {
  int k = threadIdx.x;
  if (k < 4) out[k] *= 1.0f / (128.0f * (float)(Tn - (1 << k)));
}

// fp32 -> bf16 (trunc) converter, 4 elems/thread
__global__ void tobf16(const float* __restrict__ s, unsigned short* __restrict__ d) {
  int i = blockIdx.x * 256 + threadIdx.x;
  float4 v = ((const float4*)s)[i];
  uint2 p; p.x = pk2(v.x, v.y); p.y = pk2(v.z, v.w);
  ((uint2*)d)[i] = p;
}

// ---------------- v7 main kernel (R7 proven best: 1295 us main / 1364 total) ---
// One 256-thread (4-wave) block per (k,t). Wave tiles: Y 64(j)x128(g),
// Z 64(i)x64(j). X/W staged via global_load_lds from bf16 ws copies with
// XOR-16B-granule swizzle (pre-swizzled SOURCE + swizzled ds_read: both-sides).
// C consumed fp32-direct from global (C-bf16 prepass measured net-negative:
// saves ~45us in-kernel, costs ~134us conversion). 2 independent blocks/CU at
// different phases -> T5 setprio around MFMA clusters (role-diversity regime).
// LDS map per gc: [sX 16K | sW 32K] -> overlay sY [128][264]b16 (67.6K);
// sZ fp32 [128][132] overlays all at the end. sRed at 67584.
__global__ __launch_bounds__(256, 2)
void infonce_v7(const float* __restrict__ Cp, const unsigned short* __restrict__ Xb,
                const unsigned short* __restrict__ Wb, float* __restrict__ out)
{
  __shared__ __align__(16) unsigned char smem[67648];
  char* sm   = (char*)smem;
  char* sWc  = sm + 16384;
  float* sZ  = (float*)sm;
  float* sRed = (float*)(sm + 67584);

  const int tid  = threadIdx.x;
  const int lane = tid & 63;
  const int wave = tid >> 6;     // 0..3
  const int r    = lane & 15;
  const int h    = lane >> 4;    // 0..3
  const int jw   = wave >> 1;    // Y: j-half (0..1)
  const int gw   = wave & 1;     // Y: g-half (0..1)
  const int iw   = wave >> 1;    // Z: i-half
  const int jw2  = wave & 1;     // Z: j-half

  // bijective chunked XCD swizzle: nwg = 8188 = 8*1023 + 4
  const int orig = blockIdx.x;
  const int xcd  = orig & 7;
  const int loc  = orig >> 3;
  const int wg   = (xcd < 4) ? (xcd * 1024 + loc) : (4096 + (xcd - 4) * 1023 + loc);
  const int k    = wg & 3;
  const int t    = wg >> 2;
  const int tau  = 1 << k;       // TAU = {1,2,4,8}
  if (t >= Tn - tau) return;     // uniform early-exit, before any barrier
  const int s = t + tau;

  // staging lane constants (source pre-swizzle: granule colg = (l&7)^(l>>3))
  const int colg = (lane & 7) ^ (lane >> 3);
  const unsigned short* xlane = Xb + (size_t)(wave * 32 + (lane >> 3)) * (Tn * FXn)
                                + (size_t)s * FXn + colg * 8;
  const unsigned short* wlane = Wb + (size_t)k * (FCn * FXn)
                                + (size_t)(wave * 64 + (lane >> 3)) * FXn + colg * 8;
  char* xdst = sm  + wave * 4096;   // + i*1024 (wave-uniform)
  char* wdst = sWc + wave * 8192;   // + i*1024

  // C row pointers for Z A-frags (fp32 direct; truncated to bf16 in-regs)
  const float* cr0 = Cp + (size_t)(iw * 64 +  0 + r) * (Tn * FCn) + (size_t)t * FCn;
  const float* cr1 = Cp + (size_t)(iw * 64 + 16 + r) * (Tn * FCn) + (size_t)t * FCn;
  const float* cr2 = Cp + (size_t)(iw * 64 + 32 + r) * (Tn * FCn) + (size_t)t * FCn;
  const float* cr3 = Cp + (size_t)(iw * 64 + 48 + r) * (Tn * FCn) + (size_t)t * FCn;

  f32x4 zacc[4][4];
#pragma unroll
  for (int a = 0; a < 4; ++a)
#pragma unroll
    for (int b = 0; b < 4; ++b) zacc[a][b] = f32x4{0.f, 0.f, 0.f, 0.f};

#pragma unroll 1
  for (int gc = 0; gc < 2; ++gc) {
    f32x4 yacc[4][8];
#pragma unroll
    for (int a = 0; a < 4; ++a)
#pragma unroll
      for (int b = 0; b < 8; ++b) yacc[a][b] = f32x4{0.f, 0.f, 0.f, 0.f};

#pragma unroll 1
    for (int xc = 0; xc < 8; ++xc) {
      __syncthreads();  // prior reads of this LDS region done
      // stage X chunk 128x64 (16KB) + W chunk 256x64 (32KB), async
#pragma unroll
      for (int i = 0; i < 4; ++i)
        gll16(xlane + (size_t)(i * 8) * (Tn * FXn) + xc * 64, xdst + i * 1024);
#pragma unroll
      for (int i = 0; i < 8; ++i)
        gll16(wlane + (size_t)(gc * 256 + i * 8) * FXn + xc * 64, wdst + i * 1024);
      __syncthreads();  // vmcnt(0) drain: staged data visible
      // Y-GEMM: wave tile 64(j) x 128(g), K-chunk 64
#pragma unroll
      for (int ks = 0; ks < 2; ++ks) {
        const int cbx = (ks * 64 + h * 16) ^ ((r & 7) << 4);  // swizzled byte col
        bf16x8 ax[4], bw[8];
#pragma unroll
        for (int bm = 0; bm < 4; ++bm)
          ax[bm] = *(const bf16x8*)(sm + (jw * 64 + bm * 16 + r) * 128 + cbx);
#pragma unroll
        for (int bn = 0; bn < 8; ++bn)
          bw[bn] = *(const bf16x8*)(sWc + (gw * 128 + bn * 16 + r) * 128 + cbx);
        __builtin_amdgcn_s_setprio(1);
#pragma unroll
        for (int bm = 0; bm < 4; ++bm)
#pragma unroll
          for (int bn = 0; bn < 8; ++bn)
            yacc[bm][bn] = __builtin_amdgcn_mfma_f32_16x16x32_bf16(
                ax[bm], bw[bn], yacc[bm][bn], 0, 0, 0);
        __builtin_amdgcn_s_setprio(0);
      }
    }
    __syncthreads();  // all Y-MFMA LDS reads done before sY overlay write
    // write Y (64x128 per wave) to sY[128][264] bf16, row stride 528 B
#pragma unroll
    for (int bm = 0; bm < 4; ++bm)
#pragma unroll
      for (int bn = 0; bn < 8; ++bn)
#pragma unroll
        for (int reg = 0; reg < 4; ++reg) {
          const int row = jw * 64 + bm * 16 + h * 4 + reg;
          const int col = gw * 128 + bn * 16 + r;
          *(unsigned short*)(sm + row * 528 + col * 2) =
              (unsigned short)(__float_as_uint(yacc[bm][bn][reg]) >> 16);
        }
    __syncthreads();  // sY visible
    // Z-GEMM: wave tile 64(i) x 64(j), K = 256 (this gc's g-chunk)
#pragma unroll 2
    for (int ks2 = 0; ks2 < 8; ++ks2) {
      const int goff = gc * 256 + ks2 * 32 + h * 8;   // global g elem offset
      const int gb   = ks2 * 64 + h * 16;             // sY byte col
      bf16x8 ac[4], by[4];
      {
        float4 u0 = *(const float4*)(cr0 + goff);
        float4 v0 = *(const float4*)(cr0 + goff + 4);
        float4 u1 = *(const float4*)(cr1 + goff);
        float4 v1 = *(const float4*)(cr1 + goff + 4);
        float4 u2 = *(const float4*)(cr2 + goff);
        float4 v2 = *(const float4*)(cr2 + goff + 4);
        float4 u3 = *(const float4*)(cr3 + goff);
        float4 v3 = *(const float4*)(cr3 + goff + 4);
        ac[0] = __builtin_bit_cast(bf16x8, pack8(u0, v0));
        ac[1] = __builtin_bit_cast(bf16x8, pack8(u1, v1));
        ac[2] = __builtin_bit_cast(bf16x8, pack8(u2, v2));
        ac[3] = __builtin_bit_cast(bf16x8, pack8(u3, v3));
      }
#pragma unroll
      for (int bn = 0; bn < 4; ++bn)
        by[bn] = *(const bf16x8*)(sm + (jw2 * 64 + bn * 16 + r) * 528 + gb);
      __builtin_amdgcn_s_setprio(1);
#pragma unroll
      for (int bm = 0; bm < 4; ++bm)
#pragma unroll
        for (int bn = 0; bn < 4; ++bn)
          zacc[bm][bn] = __builtin_amdgcn_mfma_f32_16x16x32_bf16(
              ac[bm], by[bn], zacc[bm][bn], 0, 0, 0);
      __builtin_amdgcn_s_setprio(0);
    }
  }
  __syncthreads();  // all Z-MFMA sY reads done before sZ overlay
  // dump Z (128x128) to LDS fp32, stride 132
#pragma unroll
  for (int bm = 0; bm < 4; ++bm)
#pragma unroll
    for (int bn = 0; bn < 4; ++bn)
#pragma unroll
      for (int reg = 0; reg < 4; ++reg)
        sZ[(iw * 64 + bm * 16 + h * 4 + reg) * SZS + (jw2 * 64 + bn * 16 + r)] =
            zacc[bm][bn][reg];
  __syncthreads();

  // per-row lse over j (128 cols); 4 waves x 32 rows, 2 lanes per row
  const int row = wave * 32 + (lane >> 1);
  const int c0l = lane & 1;
  float mx = -3.4e38f;
#pragma unroll
  for (int m = 0; m < 64; ++m) mx = fmaxf(mx, sZ[row * SZS + c0l + m * 2]);
  mx = fmaxf(mx, __shfl_xor(mx, 1));
  float sum = 0.f;
#pragma unroll
  for (int m = 0; m < 64; ++m) sum += __expf(sZ[row * SZS + c0l + m * 2] - mx);
  sum += __shfl_xor(sum, 1);
  float val = (c0l == 0) ? (sZ[row * SZS + row] - (__logf(sum) + mx)) : 0.f;
#pragma unroll
  for (int off = 1; off < 64; off <<= 1) val += __shfl_xor(val, off);
  if (lane == 0) sRed[wave] = val;
  __syncthreads();
  if (tid == 0) atomicAdd(out + k, sRed[0] + sRed[1] + sRed[2] + sRed[3]);
}

// ---------------- R5 fallback kernel (proven 1483 us) --------------------------
template <bool WBF>
__global__ __launch_bounds__(512, 4)
void infonce_main(const float* __restrict__ Cp, const float* __restrict__ Xp,
                  const void* __restrict__ Wp, float* __restrict__ out)
{
  __shared__ __align__(16) unsigned char smem[71680];
  unsigned short* sX = (unsigned short*)(smem);
  unsigned short* sW = (unsigned short*)(smem + 18432);
  unsigned short* sY = (unsigned short*)(smem + 36864);
  unsigned short* sC = (unsigned short*)(smem);
  float* sZ   = (float*)(smem);
  float* sRed = (float*)(smem + 67584);

  const int tid  = threadIdx.x;
  const int lane = tid & 63;
  const int wave = tid >> 6;
  const int r    = lane & 15;
  const int h    = lane >> 4;
  const int wr   = wave >> 1;
  const int wc   = wave & 1;

  const int orig = blockIdx.x;
  const int xcd  = orig & 7;
  const int loc  = orig >> 3;
  const int wg   = (xcd < 4) ? (xcd * 1024 + loc) : (4096 + (xcd - 4) * 1023 + loc);
  const int k    = wg & 3;
  const int t    = wg >> 2;
  const int tau  = 1 << k;
  if (t >= Tn - tau) return;

  const float* Cb = Cp + (size_t)t * FCn;
  const float* Xb = Xp + (size_t)(t + tau) * FXn;

  const int srow = tid >> 2;
  const int scol = (tid & 3) * 16;
  const float* xs = Xb + (size_t)srow * (Tn * FXn) + scol;
  unsigned short* xd = sX + srow * SXW + scol;
  unsigned short* wd = sW + srow * SXW + scol;
  const unsigned short* wsh = (const unsigned short*)Wp + (size_t)k * (FCn * FXn)
                              + (size_t)srow * FXn + scol;
  const float* wsf = (const float*)Wp + (size_t)k * (FCn * FXn)
                     + (size_t)srow * FXn + scol;
  const int crow0 = tid >> 4;
  const int ccol  = (tid & 15) * 8;
  const float* cs = Cb + (size_t)crow0 * (Tn * FCn) + ccol;
  unsigned short* cd = sC + crow0 * SYC + ccol;
  const size_t cstep = (size_t)32 * Tn * FCn;

  float4 px0, px1, px2, px3;
  float4 pw0, pw1, pw2, pw3;
  uint4  pb0, pb1;
  float4 pc0, pc1, pc2, pc3, pc4, pc5, pc6, pc7;

#define LOAD_X(XC) do { \
    const float4* _p = (const float4*)(xs + (XC) * 64); \
    px0 = _p[0]; px1 = _p[1]; px2 = _p[2]; px3 = _p[3]; } while (0)
#define LOAD_W(GC, XC) do { \
    if constexpr (WBF) { \
      const uint4* _p = (const uint4*)(wsh + (size_t)((GC) * 128) * FXn + (XC) * 64); \
      pb0 = _p[0]; pb1 = _p[1]; \
    } else { \
      const float4* _p = (const float4*)(wsf + (size_t)((GC) * 128) * FXn + (XC) * 64); \
      pw0 = _p[0]; pw1 = _p[1]; pw2 = _p[2]; pw3 = _p[3]; } } while (0)
#define STORE_XW() do { \
    *(uint4*)(xd)     = pack8(px0, px1); \
    *(uint4*)(xd + 8) = pack8(px2, px3); \
    if constexpr (WBF) { *(uint4*)(wd) = pb0; *(uint4*)(wd + 8) = pb1; } \
    else { *(uint4*)(wd) = pack8(pw0, pw1); *(uint4*)(wd + 8) = pack8(pw2, pw3); } \
  } while (0)
#define MFMA_YF() do { \
    _Pragma("unroll") \
    for (int ks = 0; ks < 2; ++ks) { \
      const int xoo = ks * 32 + h * 8; \
      bf16x8 a0 = *(const bf16x8*)(sX + (wr * 32 + 0  + r) * SXW + xoo); \
      bf16x8 a1 = *(const bf16x8*)(sX + (wr * 32 + 16 + r) * SXW + xoo); \
      _Pragma("unroll") \
      for (int bg = 0; bg < 4; ++bg) { \
        bf16x8 bb = *(const bf16x8*)(sW + (wc * 64 + bg * 16 + r) * SXW + xoo); \
        yacc[0][bg] = __builtin_amdgcn_mfma_f32_16x16x32_bf16(a0, bb, yacc[0][bg], 0, 0, 0); \
        yacc[1][bg] = __builtin_amdgcn_mfma_f32_16x16x32_bf16(a1, bb, yacc[1][bg], 0, 0, 0); \
      } } } while (0)

  f32x4 zacc[2][4];
#pragma unroll
  for (int a = 0; a < 2; ++a)
#pragma unroll
    for (int b = 0; b < 4; ++b) zacc[a][b] = f32x4{0.f, 0.f, 0.f, 0.f};

  LOAD_X(0); LOAD_W(0, 0);

  for (int gc = 0; gc < 4; ++gc) {
    f32x4 yacc[2][4];
#pragma unroll
    for (int a = 0; a < 2; ++a)
#pragma unroll
      for (int b = 0; b < 4; ++b) yacc[a][b] = f32x4{0.f, 0.f, 0.f, 0.f};

    for (int xc = 0; xc < 7; ++xc) {
      __syncthreads();
      STORE_XW();
      __syncthreads();
      LOAD_X(xc + 1); LOAD_W(gc, xc + 1);
      MFMA_YF();
    }
    __syncthreads();
    STORE_XW();
    __syncthreads();
    {
      const float4* p0 = (const float4*)(cs + 0 * cstep + gc * 128);
      const float4* p1 = (const float4*)(cs + 1 * cstep + gc * 128);
      const float4* p2 = (const float4*)(cs + 2 * cstep + gc * 128);
      const float4* p3 = (const float4*)(cs + 3 * cstep + gc * 128);
      pc0 = p0[0]; pc1 = p0[1];
      pc2 = p1[0]; pc3 = p1[1];
      pc4 = p2[0]; pc5 = p2[1];
      pc6 = p3[0]; pc7 = p3[1];
    }
    MFMA_YF();

#pragma unroll
    for (int aj = 0; aj < 2; ++aj)
#pragma unroll
      for (int bg = 0; bg < 4; ++bg)
#pragma unroll
        for (int reg = 0; reg < 4; ++reg)
          sY[(wr * 32 + aj * 16 + h * 4 + reg) * SYC + (wc * 64 + bg * 16 + r)] =
              (unsigned short)(__float_as_uint(yacc[aj][bg][reg]) >> 16);
    __syncthreads();
    *(uint4*)(cd + 0 * 32 * SYC) = pack8(pc0, pc1);
    *(uint4*)(cd + 1 * 32 * SYC) = pack8(pc2, pc3);
    *(uint4*)(cd + 2 * 32 * SYC) = pack8(pc4, pc5);
    *(uint4*)(cd + 3 * 32 * SYC) = pack8(pc6, pc7);
    __syncthreads();
    if (gc < 3) { LOAD_X(0); LOAD_W(gc + 1, 0); }
#pragma unroll
    for (int ks = 0; ks < 4; ++ks) {
      const int go = ks * 32 + h * 8;
      bf16x8 a0 = *(const bf16x8*)(sC + (wr * 32 + 0  + r) * SYC + go);
      bf16x8 a1 = *(const bf16x8*)(sC + (wr * 32 + 16 + r) * SYC + go);
#pragma unroll
      for (int bj = 0; bj < 4; ++bj) {
        bf16x8 bb = *(const bf16x8*)(sY + (wc * 64 + bj * 16 + r) * SYC + go);
        zacc[0][bj] = __builtin_amdgcn_mfma_f32_16x16x32_bf16(a0, bb, zacc[0][bj], 0, 0, 0);
        zacc[1][bj] = __builtin_amdgcn_mfma_f32_16x16x32_bf16(a1, bb, zacc[1][bj], 0, 0, 0);
      }
    }
  }
  __syncthreads();
#pragma unroll
  for (int ai = 0; ai < 2; ++ai)
#pragma unroll
    for (int bj = 0; bj < 4; ++bj)
#pragma unroll
      for (int reg = 0; reg < 4; ++reg)
        sZ[(wr * 32 + ai * 16 + h * 4 + reg) * SZS + (wc * 64 + bj * 16 + r)] =
            zacc[ai][bj][reg];
  __syncthreads();

  const int row = wave * 16 + (lane >> 2);
  const int c0l = lane & 3;
  float mx = -3.4e38f;
#pragma unroll
  for (int m = 0; m < 32; ++m) mx = fmaxf(mx, sZ[row * SZS + c0l + m * 4]);
  mx = fmaxf(mx, __shfl_xor(mx, 1));
  mx = fmaxf(mx, __shfl_xor(mx, 2));
  float sum = 0.f;
#pragma unroll
  for (int m = 0; m < 32; ++m) sum += __expf(sZ[row * SZS + c0l + m * 4] - mx);
  sum += __shfl_xor(sum, 1);
  sum += __shfl_xor(sum, 2);
  float val = (c0l == 0) ? (sZ[row * SZS + row] - (__logf(sum) + mx)) : 0.f;
#pragma unroll
  for (int off = 1; off < 64; off <<= 1) val += __shfl_xor(val, off);
  if (lane == 0) sRed[wave] = val;
  __syncthreads();
  if (tid == 0) {
    float bs = 0.f;
#pragma unroll
    for (int w2 = 0; w2 < 8; ++w2) bs += sRed[w2];
    atomicAdd(out + k, bs);
  }
#undef LOAD_X
#undef LOAD_W
#undef STORE_XW
#undef MFMA_YF
}

extern "C" void kernel_launch(void* const* d_in, const int* in_sizes, int n_in,
                              void* d_out, int out_size, void* d_ws, size_t ws_size,
                              hipStream_t stream) {
  const float* C = (const float*)d_in[0];
  const float* X = (const float*)d_in[1];
  const float* W = (const float*)d_in[2];
  // d_in[3] (bias) intentionally unused: j-independent bias cancels in Zdiag - lse
  float* out = (float*)d_out;

  const size_t NX = (size_t)128 * Tn * FXn;        // 134,217,728 elems (X)
  const size_t NW = (size_t)4 * FCn * FXn;         // 1,048,576 elems
  const size_t WS_W   = NW * 2;                    // 2 MB
  const size_t WS_MID = WS_W + NX * 2;             // + Xbf = 270,532,608

  hipLaunchKernelGGL(zero4, dim3(1), dim3(64), 0, stream, out);

  if (ws_size >= WS_MID) {
    unsigned short* Wbf = (unsigned short*)d_ws;
    unsigned short* Xbf = (unsigned short*)((char*)d_ws + WS_W);
    hipLaunchKernelGGL(tobf16, dim3((unsigned)(NW / 1024)), dim3(256), 0, stream, W, Wbf);
    hipLaunchKernelGGL(tobf16, dim3((unsigned)(NX / 1024)), dim3(256), 0, stream, X, Xbf);
    hipLaunchKernelGGL(infonce_v7, dim3(2047 * 4), dim3(256), 0, stream,
                       C, Xbf, Wbf, out);
  } else if (ws_size >= WS_W) {
    hipLaunchKernelGGL(tobf16, dim3((unsigned)(NW / 1024)), dim3(256), 0, stream,
                       W, (unsigned short*)d_ws);
    hipLaunchKernelGGL(infonce_main<true>, dim3(2047 * 4), dim3(512), 0, stream,
                       C, X, (const void*)d_ws, out);
  } else {
    hipLaunchKernelGGL(infonce_main<false>, dim3(2047 * 4), dim3(512), 0, stream,
                       C, X, (const void*)W, out);
  }
  hipLaunchKernelGGL(finalize4, dim3(1), dim3(64), 0, stream, out);
}